// Round 1
// baseline (343.222 us; speedup 1.0000x reference)
//
#include <hip/hip_runtime.h>
#include <hip/hip_bf16.h>
#include <stdint.h>

#define NV 40962     // vertices
#define NC 64        // in channels
#define NO 64        // out channels
#define NM 27        // neighbors*3
#define NB 4         // batch
#define KP 640       // padded K: t' = c*10 + k, k<9 real, slot 9 = zero
#define FROW 648     // feat LDS row stride (ushorts): 640 data + 8 pad, rows 16B-aligned

using frag16 = __attribute__((ext_vector_type(8))) short;  // 8 bf16 (4 VGPRs)
using f32x4  = __attribute__((ext_vector_type(4))) float;  // MFMA acc

__device__ inline float bf2f(unsigned short u) {
    union { unsigned int i; float f; } c; c.i = ((unsigned int)u) << 16; return c.f;
}
__device__ inline unsigned short f2bf(float f) {
    union { float f; unsigned int i; } c; c.f = f;
    unsigned int x = c.i;
    return (unsigned short)((x + 0x7FFFu + ((x >> 16) & 1u)) >> 16);  // RNE
}

// ---- W (64 x 576) fp32 -> Wp (64 x 640) bf16, K padded c*10+k ----
__global__ __launch_bounds__(256) void wprep_kernel(const float* __restrict__ W,
                                                    unsigned short* __restrict__ Wp) {
    int i = blockIdx.x * 256 + threadIdx.x;
    if (i >= NO * KP) return;
    int o = i / KP, t = i % KP;
    int c = t / 10, k = t % 10;
    float v = (k < 9) ? W[o * 576 + c * 9 + k] : 0.f;
    Wp[i] = f2bf(v);
}

// ---- x (B,C,V) fp32 -> xt (B,V,C) bf16 ----
__global__ __launch_bounds__(256) void transpose_kernel(const float* __restrict__ x,
                                                        unsigned short* __restrict__ xt) {
    __shared__ float tile[64][65];
    int b = blockIdx.y;
    int v0 = blockIdx.x * 64;
    int tv = threadIdx.x & 63;
    int tc = threadIdx.x >> 6;  // 0..3
    const float* xb = x + (size_t)b * NC * NV;
    #pragma unroll
    for (int i = 0; i < 16; i++) {
        int c = tc + i * 4;
        int v = v0 + tv;
        tile[c][tv] = (v < NV) ? xb[(size_t)c * NV + v] : 0.f;
    }
    __syncthreads();
    unsigned short* xtb = xt + (size_t)b * NV * NC;
    #pragma unroll
    for (int i = 0; i < 16; i++) {
        int vl = tc + i * 4;
        int v = v0 + vl;
        if (v < NV) xtb[(size_t)v * NC + tv] = f2bf(tile[tv][vl]);
    }
}

// ---- fused gather + MFMA GEMM ----
// block = 128 (2 waves); each wave: 16 vertices x 64 outputs
__global__ __launch_bounds__(128) void fused_kernel(
    const unsigned short* __restrict__ xt,
    const int* __restrict__ nidx,
    const float* __restrict__ nwt,
    const unsigned short* __restrict__ Wp,
    const float* __restrict__ bias,
    float* __restrict__ out)
{
    __shared__ unsigned short feat[32 * FROW];  // 41.5 KB
    int wave = threadIdx.x >> 6;
    int lane = threadIdx.x & 63;
    int b = blockIdx.y;
    int n0w = blockIdx.x * 32 + wave * 16;
    const unsigned short* xb = xt + (size_t)b * NV * NC;

    // ---- gather: lane = channel c; per vertex acc over 27 neighbors into 9 k-slots
    for (int vv = 0; vv < 16; vv++) {
        int n = n0w + vv;
        float acc[9];
        #pragma unroll
        for (int k = 0; k < 9; k++) acc[k] = 0.f;
        if (n < NV) {
            const int* ip = nidx + n * NM;
            const float* wp = nwt + n * NM;
            #pragma unroll
            for (int m = 0; m < NM; m++) {
                int id = ip[m];               // wave-uniform -> 1 line
                float w = wp[m];
                acc[m / 3] += w * bf2f(xb[(size_t)id * NC + lane]);  // 128B/wave line
            }
        }
        // pack 9 bf16 (+1 zero pad) -> 5 dwords at t' = c*10..c*10+9
        unsigned int u[5];
        #pragma unroll
        for (int p = 0; p < 4; p++)
            u[p] = (unsigned int)f2bf(acc[2 * p]) | ((unsigned int)f2bf(acc[2 * p + 1]) << 16);
        u[4] = (unsigned int)f2bf(acc[8]);
        unsigned int* dst = (unsigned int*)&feat[(wave * 16 + vv) * FROW + lane * 10];
        #pragma unroll
        for (int p = 0; p < 5; p++) dst[p] = u[p];
    }
    __syncthreads();

    // ---- GEMM: A = feat (16 vertices x 640), B = Wp rows (o x 640), 20 k-steps
    int m = lane & 15, q = lane >> 4;
    const unsigned short* arow = feat + (size_t)(wave * 16 + m) * FROW + q * 8;
    const unsigned short* wrow = Wp + q * 8;
    f32x4 acc0 = {0.f, 0.f, 0.f, 0.f};
    f32x4 acc1 = {0.f, 0.f, 0.f, 0.f};
    f32x4 acc2 = {0.f, 0.f, 0.f, 0.f};
    f32x4 acc3 = {0.f, 0.f, 0.f, 0.f};
    #pragma unroll 4
    for (int kk = 0; kk < 20; kk++) {
        frag16 a  = *(const frag16*)(arow + kk * 32);
        frag16 b0 = *(const frag16*)(wrow + (size_t)(0 * 16 + m) * KP + kk * 32);
        frag16 b1 = *(const frag16*)(wrow + (size_t)(1 * 16 + m) * KP + kk * 32);
        frag16 b2 = *(const frag16*)(wrow + (size_t)(2 * 16 + m) * KP + kk * 32);
        frag16 b3 = *(const frag16*)(wrow + (size_t)(3 * 16 + m) * KP + kk * 32);
        acc0 = __builtin_amdgcn_mfma_f32_16x16x32_bf16(a, b0, acc0, 0, 0, 0);
        acc1 = __builtin_amdgcn_mfma_f32_16x16x32_bf16(a, b1, acc1, 0, 0, 0);
        acc2 = __builtin_amdgcn_mfma_f32_16x16x32_bf16(a, b2, acc2, 0, 0, 0);
        acc3 = __builtin_amdgcn_mfma_f32_16x16x32_bf16(a, b3, acc3, 0, 0, 0);
    }

    // ---- epilogue: D[row=(q*4+i) vertex][col=m+16j output], + bias, store
    size_t outb = (size_t)b * NO * NV;
    f32x4 accs[4] = {acc0, acc1, acc2, acc3};
    #pragma unroll
    for (int j = 0; j < 4; j++) {
        int o = j * 16 + m;
        float bo = bias[o];
        #pragma unroll
        for (int i = 0; i < 4; i++) {
            int n = n0w + q * 4 + i;
            if (n < NV) out[outb + (size_t)o * NV + n] = accs[j][i] + bo;
        }
    }
}

extern "C" void kernel_launch(void* const* d_in, const int* in_sizes, int n_in,
                              void* d_out, int out_size, void* d_ws, size_t ws_size,
                              hipStream_t stream) {
    const float* x    = (const float*)d_in[0];  // (4,64,40962) fp32
    const int*   nidx = (const int*)d_in[1];    // (40962,27) int32
    const float* nwt  = (const float*)d_in[2];  // (40962,27) fp32
    const float* W    = (const float*)d_in[3];  // (64,576) fp32
    const float* bias = (const float*)d_in[4];  // (64,) fp32
    float* out = (float*)d_out;                 // (4,64,40962) fp32

    unsigned short* Wp = (unsigned short*)d_ws;                         // 80 KB
    unsigned short* xt = (unsigned short*)((char*)d_ws + 131072);       // 21 MB

    wprep_kernel<<<dim3((NO * KP + 255) / 256), 256, 0, stream>>>(W, Wp);
    transpose_kernel<<<dim3((NV + 63) / 64, NB), 256, 0, stream>>>(x, xt);
    fused_kernel<<<dim3((NV + 31) / 32, NB), 128, 0, stream>>>(xt, nidx, nwt, Wp, bias, out);
}

// Round 2
// 263.063 us; speedup vs baseline: 1.3047x; 1.3047x over previous
//
#include <hip/hip_runtime.h>
#include <hip/hip_bf16.h>
#include <stdint.h>
#include <string.h>

#define NV 40962     // vertices
#define NC 64        // in channels
#define NO 64        // out channels
#define NM 27        // neighbors*3
#define NB 4         // batch
#define KP 576       // K = 9*64, permuted t = k*64 + c (k-major)
#define ROW 584      // feat LDS row stride in ushorts; 584*2=1168 B -> bank shift 4/row

using frag16 = __attribute__((ext_vector_type(8))) short;  // 8 bf16 (4 VGPRs)
using f32x4  = __attribute__((ext_vector_type(4))) float;  // MFMA acc

__device__ inline float bfbits(unsigned int hi16) {
    union { unsigned int i; float f; } c; c.i = hi16; return c.f;
}
__device__ inline unsigned int pack_bf2(float a, float b) {
    float2 f2 = make_float2(a, b);
    __hip_bfloat162 h = __float22bfloat162_rn(f2);
    unsigned int u; memcpy(&u, &h, 4); return u;
}

// ---- W (64 x 576) fp32 -> Wp (64 x 576) bf16, K permuted t = k*64 + c ----
__global__ __launch_bounds__(256) void wprep_kernel(const float* __restrict__ W,
                                                    unsigned short* __restrict__ Wp) {
    int i = blockIdx.x * 256 + threadIdx.x;
    if (i >= NO * KP) return;
    int o = i / KP, t = i % KP;
    int k = t >> 6, c = t & 63;
    float2 f2 = make_float2(W[o * 576 + c * 9 + k], 0.f);
    __hip_bfloat162 h = __float22bfloat162_rn(f2);
    unsigned int u; memcpy(&u, &h, 4);
    Wp[i] = (unsigned short)(u & 0xffffu);
}

// ---- x (B,C,V) fp32 -> xt (B,V,C) bf16 ----
__global__ __launch_bounds__(256) void transpose_kernel(const float* __restrict__ x,
                                                        unsigned short* __restrict__ xt) {
    __shared__ float tile[64][65];
    int b = blockIdx.y;
    int v0 = blockIdx.x * 64;
    int t = threadIdx.x;
    int tv = t & 63, tc = t >> 6;
    const float* xb = x + (size_t)b * NC * NV;
    #pragma unroll
    for (int i = 0; i < 16; i++) {
        int c = tc + i * 4;
        int v = v0 + tv;
        tile[c][tv] = (v < NV) ? xb[(size_t)c * NV + v] : 0.f;
    }
    __syncthreads();
    unsigned short* xtb = xt + (size_t)b * NV * NC;
    #pragma unroll
    for (int i = 0; i < 2; i++) {
        int r = i * 32 + (t >> 3);       // vertex within tile, 0..63
        int ch0 = (t & 7) * 8;           // 8 channels per thread
        int v = v0 + r;
        if (v < NV) {
            unsigned int o[4];
            #pragma unroll
            for (int j = 0; j < 4; j++)
                o[j] = pack_bf2(tile[ch0 + 2 * j][r], tile[ch0 + 2 * j + 1][r]);
            *(uint4*)(xtb + (size_t)v * NC + ch0) = *(const uint4*)o;
        }
    }
}

// ---- fused gather + MFMA GEMM ----
// block = 128 (2 waves); each wave: 16 vertices x 64 outputs.
// Gather pass: 4 vertices at a time; lane = (v = lane>>4, cg = lane&15),
// each lane loads 4 bf16 channels (dwordx2) -> 1 instr fetches 4 vertex lines.
__global__ __launch_bounds__(128) void fused_kernel(
    const unsigned short* __restrict__ xt,
    const int* __restrict__ nidx,
    const float* __restrict__ nwt,
    const unsigned short* __restrict__ Wp,
    const float* __restrict__ bias,
    float* __restrict__ out)
{
    __shared__ unsigned short feat[32 * ROW];  // 36.5 KB -> 4 blocks/CU
    int wave = threadIdx.x >> 6;
    int lane = threadIdx.x & 63;
    int b = blockIdx.y;
    int n0w = blockIdx.x * 32 + wave * 16;
    const unsigned short* xb = xt + (size_t)b * NV * NC;

    int vsub = lane >> 4;   // 0..3
    int cg   = lane & 15;   // channels 4cg..4cg+3

    #pragma unroll
    for (int p = 0; p < 4; p++) {
        int n = n0w + p * 4 + vsub;
        int nn = (n < NV) ? n : 0;
        const int*   ip = nidx + nn * NM;
        const float* wp = nwt + nn * NM;
        float acc[9][4];
        #pragma unroll
        for (int k = 0; k < 9; k++)
            #pragma unroll
            for (int j = 0; j < 4; j++) acc[k][j] = 0.f;

        #pragma unroll
        for (int m = 0; m < NM; m++) {
            int id = ip[m];
            float w = wp[m];
            uint2 u = *(const uint2*)(xb + (size_t)id * NC + cg * 4);
            int k = m / 3;
            acc[k][0] += w * bfbits(u.x << 16);
            acc[k][1] += w * bfbits(u.x & 0xffff0000u);
            acc[k][2] += w * bfbits(u.y << 16);
            acc[k][3] += w * bfbits(u.y & 0xffff0000u);
        }

        // write 4 channels x 9 k-slots to LDS at t = k*64 + c
        int row = wave * 16 + p * 4 + vsub;
        unsigned short* dst = feat + row * ROW + cg * 4;
        #pragma unroll
        for (int k = 0; k < 9; k++) {
            unsigned int o2[2];
            o2[0] = pack_bf2(acc[k][0], acc[k][1]);
            o2[1] = pack_bf2(acc[k][2], acc[k][3]);
            *(uint2*)(dst + k * 64) = *(const uint2*)o2;
        }
    }
    __syncthreads();

    // ---- GEMM: A = feat (16 x 576) from LDS, B = Wp (64 x 576) from L1/L2
    int m = lane & 15, q = lane >> 4;
    const unsigned short* arow = feat + (size_t)(wave * 16 + m) * ROW + q * 8;
    const unsigned short* wrow = Wp + q * 8;
    f32x4 acc0 = {0.f, 0.f, 0.f, 0.f};
    f32x4 acc1 = {0.f, 0.f, 0.f, 0.f};
    f32x4 acc2 = {0.f, 0.f, 0.f, 0.f};
    f32x4 acc3 = {0.f, 0.f, 0.f, 0.f};
    #pragma unroll
    for (int kk = 0; kk < 18; kk++) {
        frag16 a  = *(const frag16*)(arow + kk * 32);
        frag16 b0 = *(const frag16*)(wrow + (size_t)(0 * 16 + m) * KP + kk * 32);
        frag16 b1 = *(const frag16*)(wrow + (size_t)(1 * 16 + m) * KP + kk * 32);
        frag16 b2 = *(const frag16*)(wrow + (size_t)(2 * 16 + m) * KP + kk * 32);
        frag16 b3 = *(const frag16*)(wrow + (size_t)(3 * 16 + m) * KP + kk * 32);
        acc0 = __builtin_amdgcn_mfma_f32_16x16x32_bf16(a, b0, acc0, 0, 0, 0);
        acc1 = __builtin_amdgcn_mfma_f32_16x16x32_bf16(a, b1, acc1, 0, 0, 0);
        acc2 = __builtin_amdgcn_mfma_f32_16x16x32_bf16(a, b2, acc2, 0, 0, 0);
        acc3 = __builtin_amdgcn_mfma_f32_16x16x32_bf16(a, b3, acc3, 0, 0, 0);
    }

    // ---- epilogue: D[row = q*4+i (vertex)][col = m+16j (output)], + bias
    size_t outb = (size_t)b * NO * NV;
    f32x4 accs[4] = {acc0, acc1, acc2, acc3};
    #pragma unroll
    for (int j = 0; j < 4; j++) {
        int o = j * 16 + m;
        float bo = bias[o];
        #pragma unroll
        for (int i = 0; i < 4; i++) {
            int n = n0w + q * 4 + i;
            if (n < NV) out[outb + (size_t)o * NV + n] = accs[j][i] + bo;
        }
    }
}

extern "C" void kernel_launch(void* const* d_in, const int* in_sizes, int n_in,
                              void* d_out, int out_size, void* d_ws, size_t ws_size,
                              hipStream_t stream) {
    const float* x    = (const float*)d_in[0];  // (4,64,40962) fp32
    const int*   nidx = (const int*)d_in[1];    // (40962,27) int32
    const float* nwt  = (const float*)d_in[2];  // (40962,27) fp32
    const float* W    = (const float*)d_in[3];  // (64,576) fp32
    const float* bias = (const float*)d_in[4];  // (64,) fp32
    float* out = (float*)d_out;                 // (4,64,40962) fp32

    unsigned short* Wp = (unsigned short*)d_ws;                     // 72 KB
    unsigned short* xt = (unsigned short*)((char*)d_ws + 131072);   // 21 MB

    wprep_kernel<<<dim3((NO * KP + 255) / 256), 256, 0, stream>>>(W, Wp);
    transpose_kernel<<<dim3((NV + 63) / 64, NB), 256, 0, stream>>>(x, xt);
    fused_kernel<<<dim3((NV + 31) / 32, NB), 128, 0, stream>>>(xt, nidx, nwt, Wp, bias, out);
}